// Round 7
// baseline (515.983 us; speedup 1.0000x reference)
//
#include <hip/hip_runtime.h>
#include <hip/hip_bf16.h>

typedef __bf16 bf16_t;
typedef __bf16 bf16x8 __attribute__((ext_vector_type(8)));
typedef float f32x4 __attribute__((ext_vector_type(4)));

#define AS1 __attribute__((address_space(1)))
#define AS3 __attribute__((address_space(3)))

__device__ __forceinline__ void gload_lds16(const void* g, void* l) {
    __builtin_amdgcn_global_load_lds((const AS1 void*)g, (AS3 void*)l, 16, 0, 0);
}

// gelu(x) = 0.5x(1+tanh(u)) = x * sigmoid(2u), u = 0.79788456(x + 0.044715x^3)
// 2u = c1*x + c2*x^3, c1 = 1.5957691216, c2 = c1*0.044715 = 0.0713548364
// => gelu = x / (1 + exp(-(c1*x + c2*x^3))).  ~8 VALU (was ~18 with full div).
__device__ __forceinline__ float gelu_f(float x) {
    float x2 = x * x;
    float t  = __builtin_fmaf(-0.0713548364f, x2, -1.5957691216f);
    float e  = __expf(x * t);               // exp(-2u); +-inf safe
    return __fdividef(x, 1.0f + e);         // fast rcp path; bf16-out tolerant
}

// ---------------------------------------------------------------------------
// Dtype detect (validated R4): low-16 exponent-field concentration test.
// flag: 1 = bf16-packed inputs, 0 = f32 inputs. (R4 evidence: f32.)
// ---------------------------------------------------------------------------
__global__ void detect_kernel(const unsigned int* __restrict__ xw,
                              int* __restrict__ flagp)
{
    __shared__ int cnt;
    int tid = threadIdx.x;
    if (tid == 0) cnt = 0;
    __syncthreads();
    unsigned int w = xw[tid];
    int le = (w >> 7) & 0xFF;
    int ok = (le >= 0x60 && le <= 0x88) ? 1 : 0;
    atomicAdd(&cnt, ok);
    __syncthreads();
    if (tid == 0) *flagp = (cnt >= 128) ? 1 : 0;
}

__device__ __forceinline__ float rd_elem(const void* p, size_t idx, int isbf) {
    return isbf ? (float)((const bf16_t*)p)[idx] : ((const float*)p)[idx];
}

// ---------------------------------------------------------------------------
// Convert x -> bf16 xb [32768*512]. One 8-elem chunk per thread.
// ---------------------------------------------------------------------------
__global__ __launch_bounds__(256) void convert_kernel(
    const void* __restrict__ x, const int* __restrict__ flagp,
    bf16_t* __restrict__ xb)
{
    const int isbf = *flagp;
    size_t i = (size_t)blockIdx.x * 256 + threadIdx.x;   // chunk id, 2097152 total
    if (isbf) {
        ((bf16x8*)xb)[i] = ((const bf16x8*)x)[i];
    } else {
        const float* s = (const float*)x + i * 8;
        float4 u0 = *(const float4*)s;
        float4 u1 = *(const float4*)(s + 4);
        bf16x8 v;
        v[0] = (bf16_t)u0.x; v[1] = (bf16_t)u0.y;
        v[2] = (bf16_t)u0.z; v[3] = (bf16_t)u0.w;
        v[4] = (bf16_t)u1.x; v[5] = (bf16_t)u1.y;
        v[6] = (bf16_t)u1.z; v[7] = (bf16_t)u1.w;
        ((bf16x8*)xb)[i] = v;
    }
}

// ---------------------------------------------------------------------------
// Weight pack -> bf16 B^T ([N,K] row-major) copies in workspace.
//  W1t [2048][512], W2t [512][2048], Wat [1024][512], Wbt [512][1024].
// ---------------------------------------------------------------------------
__global__ __launch_bounds__(256) void pack_kernel(
    const void* __restrict__ W1, const void* __restrict__ W2,
    const void* __restrict__ Wa1, const void* __restrict__ Wa2,
    const void* __restrict__ Wb1, const void* __restrict__ Wb2,
    const int* __restrict__ flagp,
    bf16_t* __restrict__ W1t, bf16_t* __restrict__ W2t,
    bf16_t* __restrict__ Wat, bf16_t* __restrict__ Wbt)
{
    const int isbf = *flagp;
    int i = blockIdx.x * 256 + threadIdx.x;
    if (i < 1048576) {                       // W1t[n][k] = W1[k][n], [512,2048]
        int n = i >> 9, k = i & 511;
        W1t[i] = (bf16_t)rd_elem(W1, (size_t)k * 2048 + n, isbf);
    } else if (i < 2097152) {                // W2t[n][k] = W2[k][n], [2048,512]
        int j = i - 1048576;
        int n = j >> 11, k = j & 2047;
        W2t[j] = (bf16_t)rd_elem(W2, (size_t)k * 512 + n, isbf);
    } else if (i < 2621440) {                // Wat[n][d] = Wa_g[e][d][h]
        int j = i - 2097152;
        int n = j >> 9, d = j & 511;
        const void* Wa = (n < 512) ? Wa1 : Wa2;
        int nn = n & 511, e = nn >> 6, hh = nn & 63;
        Wat[j] = (bf16_t)rd_elem(Wa, ((size_t)e * 512 + d) * 64 + hh, isbf);
    } else {                                 // Wbt[dout][k] = Wb_g[e][h][dout]
        int j = i - 2621440;
        int d = j >> 10, n = j & 1023;
        const void* Wb = (n < 512) ? Wb1 : Wb2;
        int nn = n & 511;
        Wbt[j] = (bf16_t)rd_elem(Wb, (size_t)nn * 512 + d, isbf);
    }
}

// ---------------------------------------------------------------------------
// Gate: masked token r in [0,16384), token = (r>>12)*8192 + 4096 + (r&4095).
// CRITICAL (R5/R6 post-mortem): logits MUST be computed from x at source
// precision (f32 path), NOT from bf16 xb — top-2 selection is discontinuous;
// bf16-rounded logits flip near-tied expert choices vs the reference.
// ---------------------------------------------------------------------------
__global__ __launch_bounds__(256) void gate_kernel(
    const void* __restrict__ xv,
    const void* __restrict__ Wg1, const void* __restrict__ Wg2,
    const int* __restrict__ flagp,
    float* __restrict__ wout)
{
    __shared__ float WgL[2][4096];   // [512][8] each, f32
    const int isbf = *flagp;
    const int tid = threadIdx.x;
    const int wave = tid >> 6, lane = tid & 63;
    for (int i = tid; i < 4096; i += 256) {
        WgL[0][i] = rd_elem(Wg1, i, isbf);
        WgL[1][i] = rd_elem(Wg2, i, isbf);
    }
    __syncthreads();

    for (int it = 0; it < 16; ++it) {
        int r = blockIdx.x * 64 + it * 4 + wave;
        int t = (r >> 12) * 8192 + 4096 + (r & 4095);
        float xr[8];
        if (isbf) {
            bf16x8 t8 = *(const bf16x8*)((const bf16_t*)xv + (size_t)t * 512 + lane * 8);
#pragma unroll
            for (int j = 0; j < 8; ++j) xr[j] = (float)t8[j];
        } else {
            const float* xp = (const float*)xv + (size_t)t * 512 + lane * 8;
            float4 u0 = *(const float4*)xp;
            float4 u1 = *(const float4*)(xp + 4);
            xr[0] = u0.x; xr[1] = u0.y; xr[2] = u0.z; xr[3] = u0.w;
            xr[4] = u1.x; xr[5] = u1.y; xr[6] = u1.z; xr[7] = u1.w;
        }
        float a[16];
#pragma unroll
        for (int e = 0; e < 16; ++e) a[e] = 0.0f;
#pragma unroll
        for (int j = 0; j < 8; ++j) {
            float xj = xr[j];
            int d = lane * 8 + j;
            const float* w1r = &WgL[0][d * 8];
            const float* w2r = &WgL[1][d * 8];
#pragma unroll
            for (int e = 0; e < 8; ++e) {
                a[e]     += xj * w1r[e];
                a[8 + e] += xj * w2r[e];
            }
        }
#pragma unroll
        for (int e = 0; e < 16; ++e) {
            a[e] += __shfl_xor(a[e], 32, 64);
            a[e] += __shfl_xor(a[e], 16, 64);
            a[e] += __shfl_xor(a[e], 8, 64);
            a[e] += __shfl_xor(a[e], 4, 64);
            a[e] += __shfl_xor(a[e], 2, 64);
            a[e] += __shfl_xor(a[e], 1, 64);
        }
        if (lane == 0) {
#pragma unroll
            for (int g = 0; g < 2; ++g) {
                float v0 = -1e30f, v1 = -1e30f;
                int i0 = 0, i1 = 0;
#pragma unroll
                for (int e = 0; e < 8; ++e) {
                    float vv = a[g * 8 + e];
                    if (vv > v0) { v0 = vv; i0 = e; }
                }
#pragma unroll
                for (int e = 0; e < 8; ++e) {
                    float vv = a[g * 8 + e];
                    if (e != i0 && vv > v1) { v1 = vv; i1 = e; }
                }
                float e1 = __expf(v1 - v0);
                float p0 = 1.0f / (1.0f + e1);
                float p1 = 1.0f - p0;
#pragma unroll
                for (int e = 0; e < 8; ++e)
                    wout[(size_t)r * 16 + g * 8 + e] =
                        (e == i0) ? p0 : ((e == i1) ? p1 : 0.0f);
            }
        }
    }
}

// ---------------------------------------------------------------------------
// GEMM: C = epilogue(A @ Bt^T), A/Bt bf16. R13 = R6 base (T1 XCD remap,
// 128x128, 4 waves, T2 swizzle, single-barrier loop) + VALU/latency fixes
// from the R6 audit (VALUBusy 51% = ~64% of wall is VALU issue):
//  1. Hoisted staging pointers: per-thread row/swizzle loop-invariant; 4
//     global ptrs advance +32 elems/iter (~8 VALU/iter, was ~45 of
//     v_lshl_add_u64 — m97 asm histogram shows compiler does NOT hoist).
//  2. Depth-2 prefetch, 3 LDS buffers (48KB): stage(t+2) at top of iter t;
//     end-of-iter wait vmcnt(4) (vmcnt(0) only last two iters). Issue-to-
//     wait distance ~2 iters (~1000cy cover vs ~150 at depth-1).
//     Wait audit: steady outstanding=8 -> vmcnt(4) retires exactly tile
//     t+1's 4 (oldest); tail: t+2==nK -> only t+1 outstanding -> vmcnt(0).
//  3. Epilogue VALU cut: cheap gelu (~8 VALU, algebraically identical);
//     bias hoisted to 4 loads (was 64); wgt hoisted to 16 (col>>6 is
//     c-invariant: c*16+ln15<64); stores share base per (r,v), c*16 folds
//     into offset imm.
// EPI: 0 = +bias, store out (flag dtype)   [FFN2]
//      1 = gelu(+bias), bf16               [FFN1]
//      2 = gelu * wgt[grow*16+wcol]        [MoE up]
//      3 = +=C masked (row&8191)>=id       [MoE down]
// ROWMAP: 0 identity(+off); 1 A-rows tokenmapped; 2 C-rows tokenmapped.
// ---------------------------------------------------------------------------
template <int EPI, int ROWMAP>
__global__ __launch_bounds__(256, 2) void gemm_kernel(
    const bf16_t* __restrict__ A, int lda,
    const bf16_t* __restrict__ Bt, int ldb,
    void* __restrict__ Cv, int ldc, int K,
    int off1, int off2,
    const void* __restrict__ biasv,
    const float* __restrict__ wgt,
    const int* __restrict__ id_ptr,
    const int* __restrict__ flagp)
{
    __shared__ __align__(16) bf16_t As[3][128 * 32];   // 8 KB per buf, x3
    __shared__ __align__(16) bf16_t Bs[3][128 * 32];   // total 48 KB

    const int isbf = *flagp;
    const int tid = threadIdx.x;
    const int lane = tid & 63;
    const int wave = tid >> 6;
    const int wm = wave >> 1, wn = wave & 1;
    const int ln15 = lane & 15, lg = lane >> 4;
    const int rsw = (ln15 >> 1) & 3;        // ((fragment row)>>1)&3

    // --- T1 XCD-chunked remap (R4-verified: FETCH 131->49MB) ---
    const int gy = gridDim.y;
    const int nwg = gridDim.x * gy;
    const int orig = blockIdx.y * gridDim.x + blockIdx.x;  // HW linear order
    const int wg = (orig & 7) * (nwg >> 3) + (orig >> 3);  // XCD-contiguous
    const int bx = wg / gy;          // M row-panel (held across gy blocks)
    const int by = wg % gy;          // N col-tile, fastest within XCD

    const int r0 = bx * 128;
    const int c0 = by * 128;
    int rA0, rC0, grow0;
    if (ROWMAP == 0) {
        rA0 = off1 + r0; rC0 = off2 + r0; grow0 = 0;
    } else if (ROWMAP == 1) {
        int g = off1 + r0;
        rA0 = (g >> 12) * 8192 + 4096 + (g & 4095);
        rC0 = r0; grow0 = g;
    } else {
        int g = off1 + r0;
        rA0 = r0; grow0 = 0;
        rC0 = (g >> 12) * 8192 + 4096 + (g & 4095);
    }

    // Hoisted staging state. Chunk i=0: row=tid>>2; i=1: row=64+(tid>>2)
    // (same swizzle gc: ((64+r)>>1)&3 == ((r>>1)+32)&3 == (r>>1)&3).
    const int srow = tid >> 2;
    const int sgc  = (tid & 3) ^ ((srow >> 1) & 3);      // T2 [rule #21]
    const bf16_t* pA0 = A  + (size_t)(rA0 + srow)      * lda + sgc * 8;
    const bf16_t* pA1 = A  + (size_t)(rA0 + 64 + srow) * lda + sgc * 8;
    const bf16_t* pB0 = Bt + (size_t)(c0  + srow)      * ldb + sgc * 8;
    const bf16_t* pB1 = Bt + (size_t)(c0  + 64 + srow) * ldb + sgc * 8;
    char* ldsA = (char*)&As[0][0] + wave * 1024;   // HW adds lane*16
    char* ldsB = (char*)&Bs[0][0] + wave * 1024;

    auto stage = [&](int buf) {
        char* la = ldsA + buf * 8192;
        char* lb = ldsB + buf * 8192;
        gload_lds16(pA0, la);
        gload_lds16(pA1, la + 4096);
        gload_lds16(pB0, lb);
        gload_lds16(pB1, lb + 4096);
        pA0 += 32; pA1 += 32; pB0 += 32; pB1 += 32;   // next K-tile
    };

    f32x4 acc[4][4];
#pragma unroll
    for (int r = 0; r < 4; ++r)
#pragma unroll
        for (int c = 0; c < 4; ++c)
            acc[r][c] = (f32x4){0.f, 0.f, 0.f, 0.f};

    const int nK = K >> 5;                  // >= 16 for all our GEMMs
    stage(0); stage(1);                     // tiles 0,1 -> bufs 0,1
    asm volatile("s_waitcnt vmcnt(4)" ::: "memory");   // tile 0 landed
    __builtin_amdgcn_s_barrier();

    // Swizzled fragment read bases (r*512 / c*512 elem offsets fold to imm).
    const bf16_t* Ard = &As[0][0] + (wm * 64 + ln15) * 32 + (lg ^ rsw) * 8;
    const bf16_t* Brd = &Bs[0][0] + (wn * 64 + ln15) * 32 + (lg ^ rsw) * 8;

    int rb = 0, sb = 2;                     // read buf, stage buf (mod 3)
    for (int kt = 0; kt < nK; ++kt) {
        if (kt + 2 < nK) stage(sb);

        const bf16_t* Ab = Ard + rb * 4096;
        const bf16_t* Bb = Brd + rb * 4096;
        bf16x8 af[4], bfr[4];
#pragma unroll
        for (int r = 0; r < 4; ++r)
            af[r] = *(const bf16x8*)(Ab + r * 512);
#pragma unroll
        for (int c = 0; c < 4; ++c)
            bfr[c] = *(const bf16x8*)(Bb + c * 512);
#pragma unroll
        for (int r = 0; r < 4; ++r)
#pragma unroll
            for (int c = 0; c < 4; ++c)
                acc[r][c] = __builtin_amdgcn_mfma_f32_16x16x32_bf16(
                    af[r], bfr[c], acc[r][c], 0, 0, 0);

        if (kt + 1 < nK) {
            if (kt + 2 < nK) asm volatile("s_waitcnt vmcnt(4)" ::: "memory");
            else             asm volatile("s_waitcnt vmcnt(0)" ::: "memory");
            __builtin_amdgcn_s_barrier();
        }
        rb = (rb == 2) ? 0 : rb + 1;
        sb = (sb == 2) ? 0 : sb + 1;
    }

    const int idv = (EPI == 3) ? id_ptr[0] : 0;
    bf16_t* Cb = (bf16_t*)Cv;
    float*  Cf = (float*)Cv;
    const int colb = c0 + wn * 64 + ln15;

    float bias_c[4] = {0.f, 0.f, 0.f, 0.f};
    if ((EPI == 0 || EPI == 1) && biasv) {
#pragma unroll
        for (int c = 0; c < 4; ++c)
            bias_c[c] = rd_elem(biasv, colb + c * 16, isbf);
    }
    const int wcol = (EPI == 2) ? ((c0 + wn * 64) >> 6) : 0;

#pragma unroll
    for (int r = 0; r < 4; ++r) {
#pragma unroll
        for (int v = 0; v < 4; ++v) {
            int lrow = wm * 64 + r * 16 + lg * 4 + v;   // tile-local row
            int crow = rC0 + lrow;
            size_t base = (size_t)crow * ldc + colb;
            float wrow = (EPI == 2)
                ? wgt[(size_t)(grow0 + lrow) * 16 + wcol] : 0.f;
#pragma unroll
            for (int c = 0; c < 4; ++c) {
                float val = acc[r][c][v];
                if (EPI == 0) {
                    val += bias_c[c];
                    if (isbf) Cb[base + c * 16] = (bf16_t)val;
                    else      Cf[base + c * 16] = val;
                } else if (EPI == 1) {
                    Cb[base + c * 16] = (bf16_t)gelu_f(val + bias_c[c]);
                } else if (EPI == 2) {
                    Cb[base + c * 16] = (bf16_t)(gelu_f(val) * wrow);
                } else {  // EPI == 3
                    if ((crow & 8191) >= idv) {
                        if (isbf) Cb[base + c * 16] =
                            (bf16_t)((float)Cb[base + c * 16] + val);
                        else Cf[base + c * 16] = Cf[base + c * 16] + val;
                    }
                }
            }
        }
    }
}

// ---------------------------------------------------------------------------
extern "C" void kernel_launch(void* const* d_in, const int* in_sizes, int n_in,
                              void* d_out, int out_size, void* d_ws, size_t ws_size,
                              hipStream_t stream)
{
    const void* x   = d_in[0];
    const int*  idp = (const int*)d_in[1];
    const void* W1  = d_in[2];
    const void* b1  = d_in[3];
    const void* W2  = d_in[4];
    const void* b2  = d_in[5];
    const void* Wg1 = d_in[6];
    const void* Wa1 = d_in[7];
    const void* Wb1 = d_in[8];
    const void* Wg2 = d_in[9];
    const void* Wa2 = d_in[10];
    const void* Wb2 = d_in[11];

    char* p = (char*)d_ws;
    bf16_t* W1t  = (bf16_t*)(p);                 // 2 MB
    bf16_t* W2t  = (bf16_t*)(p + 2097152);       // 2 MB
    bf16_t* Wat  = (bf16_t*)(p + 4194304);       // 1 MB
    bf16_t* Wbt  = (bf16_t*)(p + 5242880);       // 1 MB
    float*  wbuf = (float*) (p + 6291456);       // 1 MB
    int*    flagp= (int*)   (p + 7340032);       // 64 KB slot
    bf16_t* xb   = (bf16_t*)(p + 7405568);       // 32 MB bf16 x
    bf16_t* big  = (bf16_t*)(p + 40960000);      // h / moeh

    const size_t base = 40960000ull;
    size_t cap = (ws_size > base) ? ws_size - base : 0;
    int Mc = 32768;                               // FFN h chunk [Mc,2048] bf16
    while ((size_t)Mc * 4096ull > cap && Mc > 128) Mc >>= 1;
    int Mcm = 16384;                              // MoE h chunk [Mcm,1024] bf16
    while ((size_t)Mcm * 2048ull > cap && Mcm > 128) Mcm >>= 1;

    detect_kernel<<<1, 256, 0, stream>>>((const unsigned int*)x, flagp);
    convert_kernel<<<8192, 256, 0, stream>>>(x, flagp, xb);
    pack_kernel<<<12288, 256, 0, stream>>>(W1, W2, Wa1, Wa2, Wb1, Wb2, flagp,
                                           W1t, W2t, Wat, Wbt);
    gate_kernel<<<256, 256, 0, stream>>>(x, Wg1, Wg2, flagp, wbuf);

    // FFN, chunked over rows: out[m:m+Mc] = gelu(x@W1+b1)@W2 + b2
    for (int m = 0; m < 32768; m += Mc) {
        gemm_kernel<1, 0><<<dim3(Mc / 128, 16), 256, 0, stream>>>(
            xb, 512, W1t, 512, big, 2048, 512, m, 0,
            b1, nullptr, nullptr, flagp);
        gemm_kernel<0, 0><<<dim3(Mc / 128, 4), 256, 0, stream>>>(
            big, 2048, W2t, 2048, d_out, 512, 2048, 0, m,
            b2, nullptr, nullptr, flagp);
    }
    // MoE, chunked over masked rows: out[map(g)] += (gelu(x@Wa)*w)@Wb
    for (int m = 0; m < 16384; m += Mcm) {
        gemm_kernel<2, 1><<<dim3(Mcm / 128, 8), 256, 0, stream>>>(
            xb, 512, Wat, 512, big, 1024, 512, m, 0,
            nullptr, wbuf, nullptr, flagp);
        gemm_kernel<3, 2><<<dim3(Mcm / 128, 4), 256, 0, stream>>>(
            big, 1024, Wbt, 1024, d_out, 512, 1024, m, 0,
            nullptr, nullptr, idp, flagp);
    }
}

// Round 8
// 490.063 us; speedup vs baseline: 1.0529x; 1.0529x over previous
//
#include <hip/hip_runtime.h>
#include <hip/hip_bf16.h>

typedef __bf16 bf16_t;
typedef __bf16 bf16x8 __attribute__((ext_vector_type(8)));
typedef float f32x4 __attribute__((ext_vector_type(4)));

#define AS1 __attribute__((address_space(1)))
#define AS3 __attribute__((address_space(3)))

__device__ __forceinline__ void gload_lds16(const void* g, void* l) {
    __builtin_amdgcn_global_load_lds((const AS1 void*)g, (AS3 void*)l, 16, 0, 0);
}

// gelu(x) = 0.5x(1+tanh(u)) = x * sigmoid(2u), u = 0.79788456(x + 0.044715x^3)
// => gelu = x / (1 + exp(-(c1*x + c2*x^3))).  ~8 VALU.
__device__ __forceinline__ float gelu_f(float x) {
    float x2 = x * x;
    float t  = __builtin_fmaf(-0.0713548364f, x2, -1.5957691216f);
    float e  = __expf(x * t);               // exp(-2u); +-inf safe
    return __fdividef(x, 1.0f + e);
}

// ---------------------------------------------------------------------------
// Dtype detect (validated R4): low-16 exponent-field concentration test.
// flag: 1 = bf16-packed inputs, 0 = f32 inputs. (R4 evidence: f32.)
// ---------------------------------------------------------------------------
__global__ void detect_kernel(const unsigned int* __restrict__ xw,
                              int* __restrict__ flagp)
{
    __shared__ int cnt;
    int tid = threadIdx.x;
    if (tid == 0) cnt = 0;
    __syncthreads();
    unsigned int w = xw[tid];
    int le = (w >> 7) & 0xFF;
    int ok = (le >= 0x60 && le <= 0x88) ? 1 : 0;
    atomicAdd(&cnt, ok);
    __syncthreads();
    if (tid == 0) *flagp = (cnt >= 128) ? 1 : 0;
}

__device__ __forceinline__ float rd_elem(const void* p, size_t idx, int isbf) {
    return isbf ? (float)((const bf16_t*)p)[idx] : ((const float*)p)[idx];
}

// ---------------------------------------------------------------------------
// Convert x -> bf16 xb [32768*512]. One 8-elem chunk per thread.
// ---------------------------------------------------------------------------
__global__ __launch_bounds__(256) void convert_kernel(
    const void* __restrict__ x, const int* __restrict__ flagp,
    bf16_t* __restrict__ xb)
{
    const int isbf = *flagp;
    size_t i = (size_t)blockIdx.x * 256 + threadIdx.x;   // chunk id, 2097152 total
    if (isbf) {
        ((bf16x8*)xb)[i] = ((const bf16x8*)x)[i];
    } else {
        const float* s = (const float*)x + i * 8;
        float4 u0 = *(const float4*)s;
        float4 u1 = *(const float4*)(s + 4);
        bf16x8 v;
        v[0] = (bf16_t)u0.x; v[1] = (bf16_t)u0.y;
        v[2] = (bf16_t)u0.z; v[3] = (bf16_t)u0.w;
        v[4] = (bf16_t)u1.x; v[5] = (bf16_t)u1.y;
        v[6] = (bf16_t)u1.z; v[7] = (bf16_t)u1.w;
        ((bf16x8*)xb)[i] = v;
    }
}

// ---------------------------------------------------------------------------
// Weight pack -> bf16 B^T ([N,K] row-major) copies in workspace.
//  W1t [2048][512], W2t [512][2048], Wat [1024][512], Wbt [512][1024].
// ---------------------------------------------------------------------------
__global__ __launch_bounds__(256) void pack_kernel(
    const void* __restrict__ W1, const void* __restrict__ W2,
    const void* __restrict__ Wa1, const void* __restrict__ Wa2,
    const void* __restrict__ Wb1, const void* __restrict__ Wb2,
    const int* __restrict__ flagp,
    bf16_t* __restrict__ W1t, bf16_t* __restrict__ W2t,
    bf16_t* __restrict__ Wat, bf16_t* __restrict__ Wbt)
{
    const int isbf = *flagp;
    int i = blockIdx.x * 256 + threadIdx.x;
    if (i < 1048576) {                       // W1t[n][k] = W1[k][n], [512,2048]
        int n = i >> 9, k = i & 511;
        W1t[i] = (bf16_t)rd_elem(W1, (size_t)k * 2048 + n, isbf);
    } else if (i < 2097152) {                // W2t[n][k] = W2[k][n], [2048,512]
        int j = i - 1048576;
        int n = j >> 11, k = j & 2047;
        W2t[j] = (bf16_t)rd_elem(W2, (size_t)k * 512 + n, isbf);
    } else if (i < 2621440) {                // Wat[n][d] = Wa_g[e][d][h]
        int j = i - 2097152;
        int n = j >> 9, d = j & 511;
        const void* Wa = (n < 512) ? Wa1 : Wa2;
        int nn = n & 511, e = nn >> 6, hh = nn & 63;
        Wat[j] = (bf16_t)rd_elem(Wa, ((size_t)e * 512 + d) * 64 + hh, isbf);
    } else {                                 // Wbt[dout][k] = Wb_g[e][h][dout]
        int j = i - 2621440;
        int d = j >> 10, n = j & 1023;
        const void* Wb = (n < 512) ? Wb1 : Wb2;
        int nn = n & 511;
        Wbt[j] = (bf16_t)rd_elem(Wb, (size_t)nn * 512 + d, isbf);
    }
}

// ---------------------------------------------------------------------------
// Gate: masked token r in [0,16384), token = (r>>12)*8192 + 4096 + (r&4095).
// CRITICAL: logits MUST be computed from x at source precision (f32 path),
// NOT from bf16 xb — top-2 selection is discontinuous.
// ---------------------------------------------------------------------------
__global__ __launch_bounds__(256) void gate_kernel(
    const void* __restrict__ xv,
    const void* __restrict__ Wg1, const void* __restrict__ Wg2,
    const int* __restrict__ flagp,
    float* __restrict__ wout)
{
    __shared__ float WgL[2][4096];   // [512][8] each, f32
    const int isbf = *flagp;
    const int tid = threadIdx.x;
    const int wave = tid >> 6, lane = tid & 63;
    for (int i = tid; i < 4096; i += 256) {
        WgL[0][i] = rd_elem(Wg1, i, isbf);
        WgL[1][i] = rd_elem(Wg2, i, isbf);
    }
    __syncthreads();

    for (int it = 0; it < 16; ++it) {
        int r = blockIdx.x * 64 + it * 4 + wave;
        int t = (r >> 12) * 8192 + 4096 + (r & 4095);
        float xr[8];
        if (isbf) {
            bf16x8 t8 = *(const bf16x8*)((const bf16_t*)xv + (size_t)t * 512 + lane * 8);
#pragma unroll
            for (int j = 0; j < 8; ++j) xr[j] = (float)t8[j];
        } else {
            const float* xp = (const float*)xv + (size_t)t * 512 + lane * 8;
            float4 u0 = *(const float4*)xp;
            float4 u1 = *(const float4*)(xp + 4);
            xr[0] = u0.x; xr[1] = u0.y; xr[2] = u0.z; xr[3] = u0.w;
            xr[4] = u1.x; xr[5] = u1.y; xr[6] = u1.z; xr[7] = u1.w;
        }
        float a[16];
#pragma unroll
        for (int e = 0; e < 16; ++e) a[e] = 0.0f;
#pragma unroll
        for (int j = 0; j < 8; ++j) {
            float xj = xr[j];
            int d = lane * 8 + j;
            const float* w1r = &WgL[0][d * 8];
            const float* w2r = &WgL[1][d * 8];
#pragma unroll
            for (int e = 0; e < 8; ++e) {
                a[e]     += xj * w1r[e];
                a[8 + e] += xj * w2r[e];
            }
        }
#pragma unroll
        for (int e = 0; e < 16; ++e) {
            a[e] += __shfl_xor(a[e], 32, 64);
            a[e] += __shfl_xor(a[e], 16, 64);
            a[e] += __shfl_xor(a[e], 8, 64);
            a[e] += __shfl_xor(a[e], 4, 64);
            a[e] += __shfl_xor(a[e], 2, 64);
            a[e] += __shfl_xor(a[e], 1, 64);
        }
        if (lane == 0) {
#pragma unroll
            for (int g = 0; g < 2; ++g) {
                float v0 = -1e30f, v1 = -1e30f;
                int i0 = 0, i1 = 0;
#pragma unroll
                for (int e = 0; e < 8; ++e) {
                    float vv = a[g * 8 + e];
                    if (vv > v0) { v0 = vv; i0 = e; }
                }
#pragma unroll
                for (int e = 0; e < 8; ++e) {
                    float vv = a[g * 8 + e];
                    if (e != i0 && vv > v1) { v1 = vv; i1 = e; }
                }
                float e1 = __expf(v1 - v0);
                float p0 = 1.0f / (1.0f + e1);
                float p1 = 1.0f - p0;
#pragma unroll
                for (int e = 0; e < 8; ++e)
                    wout[(size_t)r * 16 + g * 8 + e] =
                        (e == i0) ? p0 : ((e == i1) ? p1 : 0.0f);
            }
        }
    }
}

// ---------------------------------------------------------------------------
// GEMM: C = epilogue(A @ Bt^T), A/Bt bf16. R14 = R7 data-path (T1 XCD remap,
// T2 swizzle, hoisted pointers, 3-buffer depth-2 counted-vmcnt pipeline,
// cheap epilogue) re-partitioned for OCCUPANCY (R7 audit: no pipe saturated,
// 2.4 blocks/CU, latency-bound):
//   512 threads = 8 waves (4M x 2N); wave tile 32x64; acc[2][4] (32 f32/ln).
//   VGPR ~80 (was 68 w/ 128-f32 acc variant at 4 waves) -> with 48KB LDS the
//   CU fits 3 blocks = 24 waves/CU = 6 waves/SIMD (was 2.4): TLP covers the
//   L2-staging (~200-300cy) and ds_read chains. LDS read cost rises 32->48KB
//   per block-step (B-frags x4 waves) -> LDS ceiling ~1.1PF >> current 554TF.
//   Staging: 1 A-chunk + 1 B-chunk per thread (2 loads/stage; steady wait
//   vmcnt(2); prologue stage(0),stage(1) -> wait vmcnt(2); tail vmcnt(0)).
// EPI: 0 = +bias, store out (flag dtype)   [FFN2]
//      1 = gelu(+bias), bf16               [FFN1]
//      2 = gelu * wgt[grow*16+wcol]        [MoE up]
//      3 = +=C masked (row&8191)>=id       [MoE down]
// ROWMAP: 0 identity(+off); 1 A-rows tokenmapped; 2 C-rows tokenmapped.
// ---------------------------------------------------------------------------
template <int EPI, int ROWMAP>
__global__ __launch_bounds__(512, 4) void gemm_kernel(
    const bf16_t* __restrict__ A, int lda,
    const bf16_t* __restrict__ Bt, int ldb,
    void* __restrict__ Cv, int ldc, int K,
    int off1, int off2,
    const void* __restrict__ biasv,
    const float* __restrict__ wgt,
    const int* __restrict__ id_ptr,
    const int* __restrict__ flagp)
{
    __shared__ __align__(16) bf16_t As[3][128 * 32];   // 8 KB per buf, x3
    __shared__ __align__(16) bf16_t Bs[3][128 * 32];   // total 48 KB

    const int isbf = *flagp;
    const int tid = threadIdx.x;
    const int lane = tid & 63;
    const int wave = tid >> 6;              // 0..7
    const int wm = wave >> 1, wn = wave & 1;   // 4M x 2N
    const int ln15 = lane & 15, lg = lane >> 4;
    const int rsw = (ln15 >> 1) & 3;        // ((fragment row)>>1)&3

    // --- T1 XCD-chunked remap (R4-verified: FETCH 131->49MB) ---
    const int gy = gridDim.y;
    const int nwg = gridDim.x * gy;
    const int orig = blockIdx.y * gridDim.x + blockIdx.x;  // HW linear order
    const int wg = (orig & 7) * (nwg >> 3) + (orig >> 3);  // XCD-contiguous
    const int bx = wg / gy;          // M row-panel (held across gy blocks)
    const int by = wg % gy;          // N col-tile, fastest within XCD

    const int r0 = bx * 128;
    const int c0 = by * 128;
    int rA0, rC0, grow0;
    if (ROWMAP == 0) {
        rA0 = off1 + r0; rC0 = off2 + r0; grow0 = 0;
    } else if (ROWMAP == 1) {
        int g = off1 + r0;
        rA0 = (g >> 12) * 8192 + 4096 + (g & 4095);
        rC0 = r0; grow0 = g;
    } else {
        int g = off1 + r0;
        rA0 = r0; grow0 = 0;
        rC0 = (g >> 12) * 8192 + 4096 + (g & 4095);
    }

    // Hoisted staging state: 512 chunks/matrix, 1 per thread.
    // Chunk cc = tid: row = tid>>2 (0..127), swizzled src k-chunk
    // gc = (tid&3)^((row>>1)&3)  [T2, rule #21: LDS linear, src swizzled].
    const int srow = tid >> 2;
    const int sgc  = (tid & 3) ^ ((srow >> 1) & 3);
    const bf16_t* pA = A  + (size_t)(rA0 + srow) * lda + sgc * 8;
    const bf16_t* pB = Bt + (size_t)(c0  + srow) * ldb + sgc * 8;
    char* ldsA = (char*)&As[0][0] + wave * 1024;   // HW adds lane*16
    char* ldsB = (char*)&Bs[0][0] + wave * 1024;

    auto stage = [&](int buf) {
        gload_lds16(pA, ldsA + buf * 8192);
        gload_lds16(pB, ldsB + buf * 8192);
        pA += 32; pB += 32;                  // next K-tile
    };

    f32x4 acc[2][4];
#pragma unroll
    for (int r = 0; r < 2; ++r)
#pragma unroll
        for (int c = 0; c < 4; ++c)
            acc[r][c] = (f32x4){0.f, 0.f, 0.f, 0.f};

    const int nK = K >> 5;                  // >= 16 for all our GEMMs
    stage(0); stage(1);                     // tiles 0,1 -> bufs 0,1
    asm volatile("s_waitcnt vmcnt(2)" ::: "memory");   // tile 0 landed
    __builtin_amdgcn_s_barrier();

    // Swizzled fragment read bases (r*512 / c*512 elem offsets fold to imm).
    const bf16_t* Ard = &As[0][0] + (wm * 32 + ln15) * 32 + (lg ^ rsw) * 8;
    const bf16_t* Brd = &Bs[0][0] + (wn * 64 + ln15) * 32 + (lg ^ rsw) * 8;

    int rb = 0, sb = 2;                     // read buf, stage buf (mod 3)
    for (int kt = 0; kt < nK; ++kt) {
        if (kt + 2 < nK) stage(sb);

        const bf16_t* Ab = Ard + rb * 4096;
        const bf16_t* Bb = Brd + rb * 4096;
        bf16x8 af[2], bfr[4];
#pragma unroll
        for (int r = 0; r < 2; ++r)
            af[r] = *(const bf16x8*)(Ab + r * 512);
#pragma unroll
        for (int c = 0; c < 4; ++c)
            bfr[c] = *(const bf16x8*)(Bb + c * 512);
#pragma unroll
        for (int r = 0; r < 2; ++r)
#pragma unroll
            for (int c = 0; c < 4; ++c)
                acc[r][c] = __builtin_amdgcn_mfma_f32_16x16x32_bf16(
                    af[r], bfr[c], acc[r][c], 0, 0, 0);

        if (kt + 1 < nK) {
            if (kt + 2 < nK) asm volatile("s_waitcnt vmcnt(2)" ::: "memory");
            else             asm volatile("s_waitcnt vmcnt(0)" ::: "memory");
            __builtin_amdgcn_s_barrier();
        }
        rb = (rb == 2) ? 0 : rb + 1;
        sb = (sb == 2) ? 0 : sb + 1;
    }

    const int idv = (EPI == 3) ? id_ptr[0] : 0;
    bf16_t* Cb = (bf16_t*)Cv;
    float*  Cf = (float*)Cv;
    const int colb = c0 + wn * 64 + ln15;

    float bias_c[4] = {0.f, 0.f, 0.f, 0.f};
    if ((EPI == 0 || EPI == 1) && biasv) {
#pragma unroll
        for (int c = 0; c < 4; ++c)
            bias_c[c] = rd_elem(biasv, colb + c * 16, isbf);
    }
    const int wcol = (EPI == 2) ? ((c0 + wn * 64) >> 6) : 0;

#pragma unroll
    for (int r = 0; r < 2; ++r) {
#pragma unroll
        for (int v = 0; v < 4; ++v) {
            int lrow = wm * 32 + r * 16 + lg * 4 + v;   // tile-local row
            int crow = rC0 + lrow;
            size_t base = (size_t)crow * ldc + colb;
            float wrow = (EPI == 2)
                ? wgt[(size_t)(grow0 + lrow) * 16 + wcol] : 0.f;
#pragma unroll
            for (int c = 0; c < 4; ++c) {
                float val = acc[r][c][v];
                if (EPI == 0) {
                    val += bias_c[c];
                    if (isbf) Cb[base + c * 16] = (bf16_t)val;
                    else      Cf[base + c * 16] = val;
                } else if (EPI == 1) {
                    Cb[base + c * 16] = (bf16_t)gelu_f(val + bias_c[c]);
                } else if (EPI == 2) {
                    Cb[base + c * 16] = (bf16_t)(gelu_f(val) * wrow);
                } else {  // EPI == 3
                    if ((crow & 8191) >= idv) {
                        if (isbf) Cb[base + c * 16] =
                            (bf16_t)((float)Cb[base + c * 16] + val);
                        else Cf[base + c * 16] = Cf[base + c * 16] + val;
                    }
                }
            }
        }
    }
}

// ---------------------------------------------------------------------------
extern "C" void kernel_launch(void* const* d_in, const int* in_sizes, int n_in,
                              void* d_out, int out_size, void* d_ws, size_t ws_size,
                              hipStream_t stream)
{
    const void* x   = d_in[0];
    const int*  idp = (const int*)d_in[1];
    const void* W1  = d_in[2];
    const void* b1  = d_in[3];
    const void* W2  = d_in[4];
    const void* b2  = d_in[5];
    const void* Wg1 = d_in[6];
    const void* Wa1 = d_in[7];
    const void* Wb1 = d_in[8];
    const void* Wg2 = d_in[9];
    const void* Wa2 = d_in[10];
    const void* Wb2 = d_in[11];

    char* p = (char*)d_ws;
    bf16_t* W1t  = (bf16_t*)(p);                 // 2 MB
    bf16_t* W2t  = (bf16_t*)(p + 2097152);       // 2 MB
    bf16_t* Wat  = (bf16_t*)(p + 4194304);       // 1 MB
    bf16_t* Wbt  = (bf16_t*)(p + 5242880);       // 1 MB
    float*  wbuf = (float*) (p + 6291456);       // 1 MB
    int*    flagp= (int*)   (p + 7340032);       // 64 KB slot
    bf16_t* xb   = (bf16_t*)(p + 7405568);       // 32 MB bf16 x
    bf16_t* big  = (bf16_t*)(p + 40960000);      // h / moeh

    const size_t base = 40960000ull;
    size_t cap = (ws_size > base) ? ws_size - base : 0;
    int Mc = 32768;                               // FFN h chunk [Mc,2048] bf16
    while ((size_t)Mc * 4096ull > cap && Mc > 128) Mc >>= 1;
    int Mcm = 16384;                              // MoE h chunk [Mcm,1024] bf16
    while ((size_t)Mcm * 2048ull > cap && Mcm > 128) Mcm >>= 1;

    detect_kernel<<<1, 256, 0, stream>>>((const unsigned int*)x, flagp);
    convert_kernel<<<8192, 256, 0, stream>>>(x, flagp, xb);
    pack_kernel<<<12288, 256, 0, stream>>>(W1, W2, Wa1, Wa2, Wb1, Wb2, flagp,
                                           W1t, W2t, Wat, Wbt);
    gate_kernel<<<256, 256, 0, stream>>>(x, Wg1, Wg2, flagp, wbuf);

    // FFN, chunked over rows: out[m:m+Mc] = gelu(x@W1+b1)@W2 + b2
    for (int m = 0; m < 32768; m += Mc) {
        gemm_kernel<1, 0><<<dim3(Mc / 128, 16), 512, 0, stream>>>(
            xb, 512, W1t, 512, big, 2048, 512, m, 0,
            b1, nullptr, nullptr, flagp);
        gemm_kernel<0, 0><<<dim3(Mc / 128, 4), 512, 0, stream>>>(
            big, 2048, W2t, 2048, d_out, 512, 2048, 0, m,
            b2, nullptr, nullptr, flagp);
    }
    // MoE, chunked over masked rows: out[map(g)] += (gelu(x@Wa)*w)@Wb
    for (int m = 0; m < 16384; m += Mcm) {
        gemm_kernel<2, 1><<<dim3(Mcm / 128, 8), 512, 0, stream>>>(
            xb, 512, Wat, 512, big, 1024, 512, m, 0,
            nullptr, wbuf, nullptr, flagp);
        gemm_kernel<3, 2><<<dim3(Mcm / 128, 4), 512, 0, stream>>>(
            big, 1024, Wbt, 1024, d_out, 512, 1024, m, 0,
            nullptr, nullptr, idp, flagp);
    }
}

// Round 9
// 462.238 us; speedup vs baseline: 1.1163x; 1.0602x over previous
//
#include <hip/hip_runtime.h>
#include <hip/hip_bf16.h>

typedef __bf16 bf16_t;
typedef __bf16 bf16x8 __attribute__((ext_vector_type(8)));
typedef float f32x4 __attribute__((ext_vector_type(4)));

#define AS1 __attribute__((address_space(1)))
#define AS3 __attribute__((address_space(3)))

__device__ __forceinline__ void gload_lds16(const void* g, void* l) {
    __builtin_amdgcn_global_load_lds((const AS1 void*)g, (AS3 void*)l, 16, 0, 0);
}

// gelu(x) = x * sigmoid(2u), 2u = c1*x + c2*x^3  => x / (1 + exp(-2u)). ~8 VALU.
__device__ __forceinline__ float gelu_f(float x) {
    float x2 = x * x;
    float t  = __builtin_fmaf(-0.0713548364f, x2, -1.5957691216f);
    float e  = __expf(x * t);               // exp(-2u); +-inf safe
    return __fdividef(x, 1.0f + e);
}

// ---------------------------------------------------------------------------
// Dtype detect (validated R4): low-16 exponent-field concentration test.
// flag: 1 = bf16-packed inputs, 0 = f32 inputs. (R4 evidence: f32.)
// ---------------------------------------------------------------------------
__global__ void detect_kernel(const unsigned int* __restrict__ xw,
                              int* __restrict__ flagp)
{
    __shared__ int cnt;
    int tid = threadIdx.x;
    if (tid == 0) cnt = 0;
    __syncthreads();
    unsigned int w = xw[tid];
    int le = (w >> 7) & 0xFF;
    int ok = (le >= 0x60 && le <= 0x88) ? 1 : 0;
    atomicAdd(&cnt, ok);
    __syncthreads();
    if (tid == 0) *flagp = (cnt >= 128) ? 1 : 0;
}

__device__ __forceinline__ float rd_elem(const void* p, size_t idx, int isbf) {
    return isbf ? (float)((const bf16_t*)p)[idx] : ((const float*)p)[idx];
}

// ---------------------------------------------------------------------------
// Convert x -> bf16 xb [32768*512]. One 8-elem chunk per thread.
// ---------------------------------------------------------------------------
__global__ __launch_bounds__(256) void convert_kernel(
    const void* __restrict__ x, const int* __restrict__ flagp,
    bf16_t* __restrict__ xb)
{
    const int isbf = *flagp;
    size_t i = (size_t)blockIdx.x * 256 + threadIdx.x;   // chunk id, 2097152 total
    if (isbf) {
        ((bf16x8*)xb)[i] = ((const bf16x8*)x)[i];
    } else {
        const float* s = (const float*)x + i * 8;
        float4 u0 = *(const float4*)s;
        float4 u1 = *(const float4*)(s + 4);
        bf16x8 v;
        v[0] = (bf16_t)u0.x; v[1] = (bf16_t)u0.y;
        v[2] = (bf16_t)u0.z; v[3] = (bf16_t)u0.w;
        v[4] = (bf16_t)u1.x; v[5] = (bf16_t)u1.y;
        v[6] = (bf16_t)u1.z; v[7] = (bf16_t)u1.w;
        ((bf16x8*)xb)[i] = v;
    }
}

// ---------------------------------------------------------------------------
// Weight pack -> bf16 B^T ([N,K] row-major) copies in workspace.
//  W1t [2048][512], W2t [512][2048], Wat [1024][512], Wbt [512][1024].
// ---------------------------------------------------------------------------
__global__ __launch_bounds__(256) void pack_kernel(
    const void* __restrict__ W1, const void* __restrict__ W2,
    const void* __restrict__ Wa1, const void* __restrict__ Wa2,
    const void* __restrict__ Wb1, const void* __restrict__ Wb2,
    const int* __restrict__ flagp,
    bf16_t* __restrict__ W1t, bf16_t* __restrict__ W2t,
    bf16_t* __restrict__ Wat, bf16_t* __restrict__ Wbt)
{
    const int isbf = *flagp;
    int i = blockIdx.x * 256 + threadIdx.x;
    if (i < 1048576) {                       // W1t[n][k] = W1[k][n], [512,2048]
        int n = i >> 9, k = i & 511;
        W1t[i] = (bf16_t)rd_elem(W1, (size_t)k * 2048 + n, isbf);
    } else if (i < 2097152) {                // W2t[n][k] = W2[k][n], [2048,512]
        int j = i - 1048576;
        int n = j >> 11, k = j & 2047;
        W2t[j] = (bf16_t)rd_elem(W2, (size_t)k * 512 + n, isbf);
    } else if (i < 2621440) {                // Wat[n][d] = Wa_g[e][d][h]
        int j = i - 2097152;
        int n = j >> 9, d = j & 511;
        const void* Wa = (n < 512) ? Wa1 : Wa2;
        int nn = n & 511, e = nn >> 6, hh = nn & 63;
        Wat[j] = (bf16_t)rd_elem(Wa, ((size_t)e * 512 + d) * 64 + hh, isbf);
    } else {                                 // Wbt[dout][k] = Wb_g[e][h][dout]
        int j = i - 2621440;
        int d = j >> 10, n = j & 1023;
        const void* Wb = (n < 512) ? Wb1 : Wb2;
        int nn = n & 511;
        Wbt[j] = (bf16_t)rd_elem(Wb, (size_t)nn * 512 + d, isbf);
    }
}

// ---------------------------------------------------------------------------
// Gate: masked token r in [0,16384), token = (r>>12)*8192 + 4096 + (r&4095).
// CRITICAL: logits MUST be computed from x at source precision (f32 path),
// NOT from bf16 xb — top-2 selection is discontinuous.
// ---------------------------------------------------------------------------
__global__ __launch_bounds__(256) void gate_kernel(
    const void* __restrict__ xv,
    const void* __restrict__ Wg1, const void* __restrict__ Wg2,
    const int* __restrict__ flagp,
    float* __restrict__ wout)
{
    __shared__ float WgL[2][4096];   // [512][8] each, f32
    const int isbf = *flagp;
    const int tid = threadIdx.x;
    const int wave = tid >> 6, lane = tid & 63;
    for (int i = tid; i < 4096; i += 256) {
        WgL[0][i] = rd_elem(Wg1, i, isbf);
        WgL[1][i] = rd_elem(Wg2, i, isbf);
    }
    __syncthreads();

    for (int it = 0; it < 16; ++it) {
        int r = blockIdx.x * 64 + it * 4 + wave;
        int t = (r >> 12) * 8192 + 4096 + (r & 4095);
        float xr[8];
        if (isbf) {
            bf16x8 t8 = *(const bf16x8*)((const bf16_t*)xv + (size_t)t * 512 + lane * 8);
#pragma unroll
            for (int j = 0; j < 8; ++j) xr[j] = (float)t8[j];
        } else {
            const float* xp = (const float*)xv + (size_t)t * 512 + lane * 8;
            float4 u0 = *(const float4*)xp;
            float4 u1 = *(const float4*)(xp + 4);
            xr[0] = u0.x; xr[1] = u0.y; xr[2] = u0.z; xr[3] = u0.w;
            xr[4] = u1.x; xr[5] = u1.y; xr[6] = u1.z; xr[7] = u1.w;
        }
        float a[16];
#pragma unroll
        for (int e = 0; e < 16; ++e) a[e] = 0.0f;
#pragma unroll
        for (int j = 0; j < 8; ++j) {
            float xj = xr[j];
            int d = lane * 8 + j;
            const float* w1r = &WgL[0][d * 8];
            const float* w2r = &WgL[1][d * 8];
#pragma unroll
            for (int e = 0; e < 8; ++e) {
                a[e]     += xj * w1r[e];
                a[8 + e] += xj * w2r[e];
            }
        }
#pragma unroll
        for (int e = 0; e < 16; ++e) {
            a[e] += __shfl_xor(a[e], 32, 64);
            a[e] += __shfl_xor(a[e], 16, 64);
            a[e] += __shfl_xor(a[e], 8, 64);
            a[e] += __shfl_xor(a[e], 4, 64);
            a[e] += __shfl_xor(a[e], 2, 64);
            a[e] += __shfl_xor(a[e], 1, 64);
        }
        if (lane == 0) {
#pragma unroll
            for (int g = 0; g < 2; ++g) {
                float v0 = -1e30f, v1 = -1e30f;
                int i0 = 0, i1 = 0;
#pragma unroll
                for (int e = 0; e < 8; ++e) {
                    float vv = a[g * 8 + e];
                    if (vv > v0) { v0 = vv; i0 = e; }
                }
#pragma unroll
                for (int e = 0; e < 8; ++e) {
                    float vv = a[g * 8 + e];
                    if (e != i0 && vv > v1) { v1 = vv; i1 = e; }
                }
                float e1 = __expf(v1 - v0);
                float p0 = 1.0f / (1.0f + e1);
                float p1 = 1.0f - p0;
#pragma unroll
                for (int e = 0; e < 8; ++e)
                    wout[(size_t)r * 16 + g * 8 + e] =
                        (e == i0) ? p0 : ((e == i1) ? p1 : 0.0f);
            }
        }
    }
}

// ---------------------------------------------------------------------------
// GEMM: C = epilogue(A @ Bt^T), A/Bt bf16. R15 geometry rebalance (R8 audit:
// LDS pipe ~2x MFMA pipe per wave at 32x64 tile):
//   BM=128, BN=256, BK=32; 512 thr = 8 waves (2M x 4N); wave tile 64x64,
//   acc[4][4] (64 f32/lane). Per wave-K-step: 16 MFMA / 8 ds_read_b128
//   (R7's 2:1 ratio) at R8-class occupancy: bufs 24KB x3 = 72KB -> 2
//   blocks/CU = 16 waves = 4/SIMD (launch_bounds(512,4) caps VGPR at 128;
//   est ~120). Barriers per FLOP halve (16 steps per 2.1 MFLOP).
//   Staging uniform: 1536 chunks / 512 thr = 3 loads/thread (1 A + 2 B);
//   counted wait vmcnt(3) (T4); depth-2, 3 buffers as R8. T2 swizzle
//   unchanged (row offsets 128 = 0 mod 4 under (row>>1)&3). T1 remap as R8.
// EPI: 0 = +bias, store out (flag dtype)   [FFN2]
//      1 = gelu(+bias), bf16               [FFN1]
//      2 = gelu * wgt[grow*16+wcol]        [MoE up]
//      3 = +=C masked (row&8191)>=id       [MoE down]
// ROWMAP: 0 identity(+off); 1 A-rows tokenmapped; 2 C-rows tokenmapped.
// ---------------------------------------------------------------------------
template <int EPI, int ROWMAP>
__global__ __launch_bounds__(512, 4) void gemm_kernel(
    const bf16_t* __restrict__ A, int lda,
    const bf16_t* __restrict__ Bt, int ldb,
    void* __restrict__ Cv, int ldc, int K,
    int off1, int off2,
    const void* __restrict__ biasv,
    const float* __restrict__ wgt,
    const int* __restrict__ id_ptr,
    const int* __restrict__ flagp)
{
    __shared__ __align__(16) bf16_t As[3][128 * 32];   //  8 KB per buf
    __shared__ __align__(16) bf16_t Bs[3][256 * 32];   // 16 KB per buf; 72 KB tot

    const int isbf = *flagp;
    const int tid = threadIdx.x;
    const int lane = tid & 63;
    const int wave = tid >> 6;              // 0..7
    const int wm = wave >> 2, wn = wave & 3;   // 2M x 4N
    const int ln15 = lane & 15, lg = lane >> 4;
    const int rsw = (ln15 >> 1) & 3;        // ((fragment row)>>1)&3

    // --- T1 XCD-chunked remap (R4-verified: FETCH 131->49MB) ---
    const int gy = gridDim.y;
    const int nwg = gridDim.x * gy;
    const int orig = blockIdx.y * gridDim.x + blockIdx.x;  // HW linear order
    const int wg = (orig & 7) * (nwg >> 3) + (orig >> 3);  // XCD-contiguous
    const int bx = wg / gy;          // M row-panel (held across gy blocks)
    const int by = wg % gy;          // N col-tile, fastest within XCD

    const int r0 = bx * 128;
    const int c0 = by * 256;
    int rA0, rC0, grow0;
    if (ROWMAP == 0) {
        rA0 = off1 + r0; rC0 = off2 + r0; grow0 = 0;
    } else if (ROWMAP == 1) {
        int g = off1 + r0;
        rA0 = (g >> 12) * 8192 + 4096 + (g & 4095);
        rC0 = r0; grow0 = g;
    } else {
        int g = off1 + r0;
        rA0 = r0; grow0 = 0;
        rC0 = (g >> 12) * 8192 + 4096 + (g & 4095);
    }

    // Hoisted staging state (T2 swizzle, rule #21: LDS linear, src swizzled).
    // A: 512 chunks (1/thread): row = tid>>2, gc = (tid&3)^((row>>1)&3).
    // B: 1024 chunks (2/thread): rows tid>>2 and 128+(tid>>2); same gc
    //    (row offset 128 = 0 mod 4 under (row>>1)&3).
    const int srow = tid >> 2;
    const int sgc  = (tid & 3) ^ ((srow >> 1) & 3);
    const bf16_t* pA  = A  + (size_t)(rA0 + srow)       * lda + sgc * 8;
    const bf16_t* pB0 = Bt + (size_t)(c0  + srow)       * ldb + sgc * 8;
    const bf16_t* pB1 = Bt + (size_t)(c0  + 128 + srow) * ldb + sgc * 8;
    char* ldsA = (char*)&As[0][0] + wave * 1024;          // HW adds lane*16
    char* ldsB = (char*)&Bs[0][0] + wave * 1024;

    auto stage = [&](int buf) {
        gload_lds16(pA,  ldsA + buf * 8192);
        gload_lds16(pB0, ldsB + buf * 16384);
        gload_lds16(pB1, ldsB + buf * 16384 + 8192);
        pA += 32; pB0 += 32; pB1 += 32;      // next K-tile
    };

    f32x4 acc[4][4];
#pragma unroll
    for (int r = 0; r < 4; ++r)
#pragma unroll
        for (int c = 0; c < 4; ++c)
            acc[r][c] = (f32x4){0.f, 0.f, 0.f, 0.f};

    const int nK = K >> 5;                  // >= 16 for all our GEMMs
    stage(0); stage(1);                     // tiles 0,1 -> bufs 0,1
    asm volatile("s_waitcnt vmcnt(3)" ::: "memory");   // tile 0 landed
    __builtin_amdgcn_s_barrier();

    // Swizzled fragment read bases (r*512 / c*512 elem offsets fold to imm).
    const bf16_t* Ard = &As[0][0] + (wm * 64 + ln15) * 32 + (lg ^ rsw) * 8;
    const bf16_t* Brd = &Bs[0][0] + (wn * 64 + ln15) * 32 + (lg ^ rsw) * 8;

    int rb = 0, sb = 2;                     // read buf, stage buf (mod 3)
    for (int kt = 0; kt < nK; ++kt) {
        if (kt + 2 < nK) stage(sb);

        const bf16_t* Ab = Ard + rb * 4096;   // 8192 B / 2
        const bf16_t* Bb = Brd + rb * 8192;   // 16384 B / 2
        bf16x8 af[4], bfr[4];
#pragma unroll
        for (int r = 0; r < 4; ++r)
            af[r] = *(const bf16x8*)(Ab + r * 512);
#pragma unroll
        for (int c = 0; c < 4; ++c)
            bfr[c] = *(const bf16x8*)(Bb + c * 512);
#pragma unroll
        for (int r = 0; r < 4; ++r)
#pragma unroll
            for (int c = 0; c < 4; ++c)
                acc[r][c] = __builtin_amdgcn_mfma_f32_16x16x32_bf16(
                    af[r], bfr[c], acc[r][c], 0, 0, 0);

        if (kt + 1 < nK) {
            if (kt + 2 < nK) asm volatile("s_waitcnt vmcnt(3)" ::: "memory");
            else             asm volatile("s_waitcnt vmcnt(0)" ::: "memory");
            __builtin_amdgcn_s_barrier();
        }
        rb = (rb == 2) ? 0 : rb + 1;
        sb = (sb == 2) ? 0 : sb + 1;
    }

    const int idv = (EPI == 3) ? id_ptr[0] : 0;
    bf16_t* Cb = (bf16_t*)Cv;
    float*  Cf = (float*)Cv;
    const int colb = c0 + wn * 64 + ln15;

    float bias_c[4] = {0.f, 0.f, 0.f, 0.f};
    if ((EPI == 0 || EPI == 1) && biasv) {
#pragma unroll
        for (int c = 0; c < 4; ++c)
            bias_c[c] = rd_elem(biasv, colb + c * 16, isbf);
    }
    const int wcol = (EPI == 2) ? ((c0 + wn * 64) >> 6) : 0;

#pragma unroll
    for (int r = 0; r < 4; ++r) {
#pragma unroll
        for (int v = 0; v < 4; ++v) {
            int lrow = wm * 64 + r * 16 + lg * 4 + v;   // tile-local row
            int crow = rC0 + lrow;
            size_t base = (size_t)crow * ldc + colb;
            float wrow = (EPI == 2)
                ? wgt[(size_t)(grow0 + lrow) * 16 + wcol] : 0.f;
#pragma unroll
            for (int c = 0; c < 4; ++c) {
                float val = acc[r][c][v];
                if (EPI == 0) {
                    val += bias_c[c];
                    if (isbf) Cb[base + c * 16] = (bf16_t)val;
                    else      Cf[base + c * 16] = val;
                } else if (EPI == 1) {
                    Cb[base + c * 16] = (bf16_t)gelu_f(val + bias_c[c]);
                } else if (EPI == 2) {
                    Cb[base + c * 16] = (bf16_t)(gelu_f(val) * wrow);
                } else {  // EPI == 3
                    if ((crow & 8191) >= idv) {
                        if (isbf) Cb[base + c * 16] =
                            (bf16_t)((float)Cb[base + c * 16] + val);
                        else Cf[base + c * 16] = Cf[base + c * 16] + val;
                    }
                }
            }
        }
    }
}

// ---------------------------------------------------------------------------
extern "C" void kernel_launch(void* const* d_in, const int* in_sizes, int n_in,
                              void* d_out, int out_size, void* d_ws, size_t ws_size,
                              hipStream_t stream)
{
    const void* x   = d_in[0];
    const int*  idp = (const int*)d_in[1];
    const void* W1  = d_in[2];
    const void* b1  = d_in[3];
    const void* W2  = d_in[4];
    const void* b2  = d_in[5];
    const void* Wg1 = d_in[6];
    const void* Wa1 = d_in[7];
    const void* Wb1 = d_in[8];
    const void* Wg2 = d_in[9];
    const void* Wa2 = d_in[10];
    const void* Wb2 = d_in[11];

    char* p = (char*)d_ws;
    bf16_t* W1t  = (bf16_t*)(p);                 // 2 MB
    bf16_t* W2t  = (bf16_t*)(p + 2097152);       // 2 MB
    bf16_t* Wat  = (bf16_t*)(p + 4194304);       // 1 MB
    bf16_t* Wbt  = (bf16_t*)(p + 5242880);       // 1 MB
    float*  wbuf = (float*) (p + 6291456);       // 1 MB
    int*    flagp= (int*)   (p + 7340032);       // 64 KB slot
    bf16_t* xb   = (bf16_t*)(p + 7405568);       // 32 MB bf16 x
    bf16_t* big  = (bf16_t*)(p + 40960000);      // h / moeh

    const size_t base = 40960000ull;
    size_t cap = (ws_size > base) ? ws_size - base : 0;
    int Mc = 32768;                               // FFN h chunk [Mc,2048] bf16
    while ((size_t)Mc * 4096ull > cap && Mc > 128) Mc >>= 1;
    int Mcm = 16384;                              // MoE h chunk [Mcm,1024] bf16
    while ((size_t)Mcm * 2048ull > cap && Mcm > 128) Mcm >>= 1;

    detect_kernel<<<1, 256, 0, stream>>>((const unsigned int*)x, flagp);
    convert_kernel<<<8192, 256, 0, stream>>>(x, flagp, xb);
    pack_kernel<<<12288, 256, 0, stream>>>(W1, W2, Wa1, Wa2, Wb1, Wb2, flagp,
                                           W1t, W2t, Wat, Wbt);
    gate_kernel<<<256, 256, 0, stream>>>(x, Wg1, Wg2, flagp, wbuf);

    // FFN, chunked over rows: out[m:m+Mc] = gelu(x@W1+b1)@W2 + b2
    for (int m = 0; m < 32768; m += Mc) {
        gemm_kernel<1, 0><<<dim3(Mc / 128, 8), 512, 0, stream>>>(
            xb, 512, W1t, 512, big, 2048, 512, m, 0,
            b1, nullptr, nullptr, flagp);
        gemm_kernel<0, 0><<<dim3(Mc / 128, 2), 512, 0, stream>>>(
            big, 2048, W2t, 2048, d_out, 512, 2048, 0, m,
            b2, nullptr, nullptr, flagp);
    }
    // MoE, chunked over masked rows: out[map(g)] += (gelu(x@Wa)*w)@Wb
    for (int m = 0; m < 16384; m += Mcm) {
        gemm_kernel<2, 1><<<dim3(Mcm / 128, 4), 512, 0, stream>>>(
            xb, 512, Wat, 512, big, 1024, 512, m, 0,
            nullptr, wbuf, nullptr, flagp);
        gemm_kernel<3, 2><<<dim3(Mcm / 128, 2), 512, 0, stream>>>(
            big, 1024, Wbt, 1024, d_out, 512, 1024, m, 0,
            nullptr, nullptr, idp, flagp);
    }
}